// Round 1
// baseline (16806.317 us; speedup 1.0000x reference)
//
#include <hip/hip_runtime.h>
#include <cmath>

#define BATCH 4
#define CH    512
#define HCH   256
#define NPIX  4096
#define L2E   1.44269504088896340736f

// ---------------------------------------------------------------------------
// Projection GEMM: Y[o,n] = W[o,:]·X[:,n] + bias, per batch.
//   o in [0,256)    -> F  [HC,N]
//   o in [256,512)  -> G  [HC,N]
//   o in [512,1024) -> V  [N,C]  (transposed store: V[n][c] = Wh-row result)
// grid (64 n-tiles, 16 o-tiles, 4 batches), 256 threads, 64x64 tile, 4x4/thr
// ---------------------------------------------------------------------------
__global__ __launch_bounds__(256) void proj_kernel(
    const float* __restrict__ x,
    const float* __restrict__ Wf, const float* __restrict__ bf,
    const float* __restrict__ Wg, const float* __restrict__ bg,
    const float* __restrict__ Wh, const float* __restrict__ bh,
    float* __restrict__ Fo, float* __restrict__ Go, float* __restrict__ Vo)
{
    __shared__ float As[16][68];   // [c][o]
    __shared__ float Bs[16][68];   // [c][n]
    const int b  = blockIdx.z;
    const int o0 = blockIdx.y * 64;
    const int n0 = blockIdx.x * 64;
    const int t  = threadIdx.x;
    const int tx = t & 15;          // n micro-tile
    const int ty = t >> 4;          // o micro-tile
    const int ar = t >> 2;          // A-loader row (o), 0..63
    const int ac = (t & 3) * 4;     // A-loader col (c), float4
    const int br = t >> 4;          // B-loader row (c), 0..15
    const int bn = (t & 15) * 4;    // B-loader col (n), float4
    const float* xb = x + (size_t)b * CH * NPIX;

    const int o_l = o0 + ar;
    const float* wrow;
    if (o_l < HCH)          wrow = Wf + (size_t)o_l * CH;
    else if (o_l < 2 * HCH) wrow = Wg + (size_t)(o_l - HCH) * CH;
    else                    wrow = Wh + (size_t)(o_l - 2 * HCH) * CH;

    float acc[4][4];
    #pragma unroll
    for (int i = 0; i < 4; ++i)
        #pragma unroll
        for (int j = 0; j < 4; ++j) acc[i][j] = 0.f;

    for (int c0 = 0; c0 < CH; c0 += 16) {
        float4 a4 = *(const float4*)(wrow + c0 + ac);
        float4 b4 = *(const float4*)(xb + (size_t)(c0 + br) * NPIX + n0 + bn);
        __syncthreads();
        As[ac + 0][ar] = a4.x;
        As[ac + 1][ar] = a4.y;
        As[ac + 2][ar] = a4.z;
        As[ac + 3][ar] = a4.w;
        *(float4*)&Bs[br][bn] = b4;
        __syncthreads();
        #pragma unroll
        for (int cc = 0; cc < 16; ++cc) {
            float4 av = *(const float4*)&As[cc][ty * 4];
            float4 bv = *(const float4*)&Bs[cc][tx * 4];
            const float a_[4] = {av.x, av.y, av.z, av.w};
            const float b_[4] = {bv.x, bv.y, bv.z, bv.w};
            #pragma unroll
            for (int i = 0; i < 4; ++i)
                #pragma unroll
                for (int j = 0; j < 4; ++j)
                    acc[i][j] += a_[i] * b_[j];
        }
    }

    #pragma unroll
    for (int i = 0; i < 4; ++i) {
        const int o = o0 + ty * 4 + i;
        float bias;
        if (o < HCH)          bias = bf[o];
        else if (o < 2 * HCH) bias = bg[o - HCH];
        else                  bias = bh[o - 2 * HCH];
        #pragma unroll
        for (int j = 0; j < 4; ++j) {
            const int n = n0 + tx * 4 + j;
            const float v = acc[i][j] + bias;
            if (o < HCH)
                Fo[((size_t)b * HCH + o) * NPIX + n] = v;
            else if (o < 2 * HCH)
                Go[((size_t)b * HCH + (o - HCH)) * NPIX + n] = v;
            else
                Vo[((size_t)b * NPIX + n) * CH + (o - 2 * HCH)] = v;
        }
    }
}

// ---------------------------------------------------------------------------
// Pass A: softmax row stats. Per block: 32 query rows, sweep 4096 keys in
// 64-wide tiles. S[q,k] = sum_c Fq[c,q]*G[c,k]. Online max/sumexp.
// grid (128 q-tiles, 4 batches), 256 threads.
// Thread S-mapping: 2 q rows (qq=(t>>4)*2) x 4 consecutive k (kk=(t&15)*4).
// ---------------------------------------------------------------------------
__global__ __launch_bounds__(256) void attn_stats_kernel(
    const float* __restrict__ F, const float* __restrict__ G,
    float* __restrict__ rowm, float* __restrict__ rowlinv)
{
    __shared__ float Fq[HCH][32];     // 32 KB: Fq[c][q]
    __shared__ float S[32][68];       // score tile, padded
    __shared__ float red[32][8];
    __shared__ float mrow[32], lrow[32], mnew[32];
    const int b  = blockIdx.y;
    const int q0 = blockIdx.x * 32;
    const int t  = threadIdx.x;
    const float* Fb = F + (size_t)b * HCH * NPIX;
    const float* Gb = G + (size_t)b * HCH * NPIX;

    for (int idx = t; idx < HCH * 32; idx += 256) {
        const int c = idx >> 5, q = idx & 31;
        Fq[c][q] = Fb[(size_t)c * NPIX + q0 + q];
    }
    if (t < 32) { mrow[t] = -3.0e38f; lrow[t] = 0.f; }
    __syncthreads();

    const int kk = (t & 15) * 4;
    const int qq = (t >> 4) * 2;
    const int rq = t >> 3;   // reduction row, 0..31
    const int l8 = t & 7;    // 8 threads per row

    for (int k0 = 0; k0 < NPIX; k0 += 64) {
        float a00 = 0.f, a01 = 0.f, a02 = 0.f, a03 = 0.f;
        float a10 = 0.f, a11 = 0.f, a12 = 0.f, a13 = 0.f;
        const float* gcol = Gb + k0 + kk;
        #pragma unroll 4
        for (int c = 0; c < HCH; ++c) {
            float4 g4 = *(const float4*)(gcol + (size_t)c * NPIX);
            const float f0 = Fq[c][qq];
            const float f1 = Fq[c][qq + 1];
            a00 += f0 * g4.x; a01 += f0 * g4.y; a02 += f0 * g4.z; a03 += f0 * g4.w;
            a10 += f1 * g4.x; a11 += f1 * g4.y; a12 += f1 * g4.z; a13 += f1 * g4.w;
        }
        __syncthreads();   // previous tile's reductions done
        *(float4*)&S[qq][kk]     = make_float4(a00, a01, a02, a03);
        *(float4*)&S[qq + 1][kk] = make_float4(a10, a11, a12, a13);
        __syncthreads();
        // tile max per row
        float lm = -3.0e38f;
        #pragma unroll
        for (int j = 0; j < 8; ++j) lm = fmaxf(lm, S[rq][l8 * 8 + j]);
        red[rq][l8] = lm;
        __syncthreads();
        if (l8 == 0) {
            float tm = red[rq][0];
            #pragma unroll
            for (int j = 1; j < 8; ++j) tm = fmaxf(tm, red[rq][j]);
            mnew[rq] = fmaxf(mrow[rq], tm);
        }
        __syncthreads();
        const float mn = mnew[rq];
        float ps = 0.f;
        #pragma unroll
        for (int j = 0; j < 8; ++j) ps += exp2f(L2E * (S[rq][l8 * 8 + j] - mn));
        red[rq][l8] = ps;
        __syncthreads();
        if (l8 == 0) {
            float ts = 0.f;
            #pragma unroll
            for (int j = 0; j < 8; ++j) ts += red[rq][j];
            const float al = exp2f(L2E * (mrow[rq] - mn));
            lrow[rq] = lrow[rq] * al + ts;
            mrow[rq] = mn;
        }
    }
    __syncthreads();
    if (t < 32) {
        rowm[(size_t)b * NPIX + q0 + t]    = mrow[t];
        rowlinv[(size_t)b * NPIX + q0 + t] = 1.0f / lrow[t];
    }
}

// ---------------------------------------------------------------------------
// Pass B: recompute S, P = exp(S-m)/l (final), accumulate:
//   - column sums -> attnacc (atomicAdd, one per key per block)
//   - O[q, 0:512] += P[q,k] * V[k, 0:512]   (thread owns q=t>>3, 64 c's)
// Writes residual out[b][c][q].
// ---------------------------------------------------------------------------
__global__ __launch_bounds__(256) void attn_apply_kernel(
    const float* __restrict__ F, const float* __restrict__ G,
    const float* __restrict__ V,
    const float* __restrict__ rowm, const float* __restrict__ rowlinv,
    float* __restrict__ outres, float* __restrict__ attnacc)
{
    __shared__ float Fq[HCH][32];
    __shared__ float P[32][68];
    __shared__ float mq[32], lq[32];
    const int b  = blockIdx.y;
    const int q0 = blockIdx.x * 32;
    const int t  = threadIdx.x;
    const float* Fb = F + (size_t)b * HCH * NPIX;
    const float* Gb = G + (size_t)b * HCH * NPIX;
    const float* Vb = V + (size_t)b * NPIX * CH;

    for (int idx = t; idx < HCH * 32; idx += 256) {
        const int c = idx >> 5, q = idx & 31;
        Fq[c][q] = Fb[(size_t)c * NPIX + q0 + q];
    }
    if (t < 32) {
        mq[t] = rowm[(size_t)b * NPIX + q0 + t];
        lq[t] = rowlinv[(size_t)b * NPIX + q0 + t];
    }
    __syncthreads();

    const int kk  = (t & 15) * 4;
    const int qq  = (t >> 4) * 2;
    const int oq  = t >> 3;         // owned q row for O
    const int oc0 = (t & 7) * 64;   // owned c range for O
    float O[64];
    #pragma unroll
    for (int i = 0; i < 64; ++i) O[i] = 0.f;

    for (int k0 = 0; k0 < NPIX; k0 += 64) {
        float a00 = 0.f, a01 = 0.f, a02 = 0.f, a03 = 0.f;
        float a10 = 0.f, a11 = 0.f, a12 = 0.f, a13 = 0.f;
        const float* gcol = Gb + k0 + kk;
        #pragma unroll 4
        for (int c = 0; c < HCH; ++c) {
            float4 g4 = *(const float4*)(gcol + (size_t)c * NPIX);
            const float f0 = Fq[c][qq];
            const float f1 = Fq[c][qq + 1];
            a00 += f0 * g4.x; a01 += f0 * g4.y; a02 += f0 * g4.z; a03 += f0 * g4.w;
            a10 += f1 * g4.x; a11 += f1 * g4.y; a12 += f1 * g4.z; a13 += f1 * g4.w;
        }
        const float m0 = mq[qq],     li0 = lq[qq];
        const float m1 = mq[qq + 1], li1 = lq[qq + 1];
        float4 p0 = make_float4(exp2f(L2E * (a00 - m0)) * li0,
                                exp2f(L2E * (a01 - m0)) * li0,
                                exp2f(L2E * (a02 - m0)) * li0,
                                exp2f(L2E * (a03 - m0)) * li0);
        float4 p1 = make_float4(exp2f(L2E * (a10 - m1)) * li1,
                                exp2f(L2E * (a11 - m1)) * li1,
                                exp2f(L2E * (a12 - m1)) * li1,
                                exp2f(L2E * (a13 - m1)) * li1);
        __syncthreads();   // previous tile's P consumers done
        *(float4*)&P[qq][kk]     = p0;
        *(float4*)&P[qq + 1][kk] = p1;
        __syncthreads();

        if (t < 64) {   // wave 0: column sums for attention
            float cs = 0.f;
            #pragma unroll
            for (int q = 0; q < 32; ++q) cs += P[q][t];
            atomicAdd(&attnacc[(size_t)b * NPIX + k0 + t], cs);
        }

        const float* Vk = Vb + (size_t)k0 * CH + oc0;
        #pragma unroll 1
        for (int k = 0; k < 64; ++k) {
            const float p = P[oq][k];
            const float* vr = Vk + (size_t)k * CH;
            #pragma unroll
            for (int cj = 0; cj < 64; cj += 4) {
                float4 v4 = *(const float4*)(vr + cj);
                O[cj + 0] += p * v4.x;
                O[cj + 1] += p * v4.y;
                O[cj + 2] += p * v4.z;
                O[cj + 3] += p * v4.w;
            }
        }
    }

    #pragma unroll
    for (int cj = 0; cj < 64; ++cj) {
        outres[((size_t)b * CH + oc0 + cj) * NPIX + q0 + oq] = O[cj];
    }
}

__global__ __launch_bounds__(256) void attn_fin_kernel(
    const float* __restrict__ acc, float* __restrict__ outa)
{
    const int i = blockIdx.x * 256 + threadIdx.x;
    if (i < BATCH * NPIX) outa[i] = acc[i] * (1.0f / (float)NPIX);
}

extern "C" void kernel_launch(void* const* d_in, const int* in_sizes, int n_in,
                              void* d_out, int out_size, void* d_ws, size_t ws_size,
                              hipStream_t stream)
{
    (void)in_sizes; (void)n_in; (void)out_size; (void)ws_size;
    const float* x  = (const float*)d_in[0];
    const float* Wf = (const float*)d_in[1];
    const float* bf = (const float*)d_in[2];
    const float* Wg = (const float*)d_in[3];
    const float* bg = (const float*)d_in[4];
    const float* Wh = (const float*)d_in[5];
    const float* bh = (const float*)d_in[6];
    float* out = (float*)d_out;
    float* ws  = (float*)d_ws;

    float* F       = ws;                                   // 4*256*4096
    float* G       = F + (size_t)BATCH * HCH * NPIX;       // 4*256*4096
    float* V       = G + (size_t)BATCH * HCH * NPIX;       // 4*4096*512
    float* rowm    = V + (size_t)BATCH * NPIX * CH;        // 4*4096
    float* rowlinv = rowm + (size_t)BATCH * NPIX;          // 4*4096
    float* attnacc = rowlinv + (size_t)BATCH * NPIX;       // 4*4096

    hipMemsetAsync(attnacc, 0, (size_t)BATCH * NPIX * sizeof(float), stream);

    dim3 g1(64, 16, BATCH);
    proj_kernel<<<g1, 256, 0, stream>>>(x, Wf, bf, Wg, bg, Wh, bh, F, G, V);

    dim3 g2(NPIX / 32, BATCH);
    attn_stats_kernel<<<g2, 256, 0, stream>>>(F, G, rowm, rowlinv);
    attn_apply_kernel<<<g2, 256, 0, stream>>>(F, G, V, rowm, rowlinv,
                                              out, attnacc);

    attn_fin_kernel<<<BATCH * NPIX / 256, 256, 0, stream>>>(
        attnacc, out + (size_t)BATCH * CH * NPIX);
}

// Round 2
// 850.943 us; speedup vs baseline: 19.7502x; 19.7502x over previous
//
#include <hip/hip_runtime.h>
#include <cmath>

#define BATCH 4
#define CH    512
#define HCH   256
#define NPIX  4096
#define L2E   1.44269504088896340736f

typedef __attribute__((ext_vector_type(8))) short bf16x8;
typedef __attribute__((ext_vector_type(4))) float f32x4;

__device__ __forceinline__ unsigned short f2bf(float f) {
    unsigned int u = __float_as_uint(f);
    unsigned int r = (u + 0x7fffu + ((u >> 16) & 1u)) >> 16;
    return (unsigned short)r;
}

// ---------------------------------------------------------------------------
// Projection GEMM (fp32 VALU): Y[o,n] = W[o,:]·X[:,n] + bias, per batch.
//   o in [0,256)    -> F  bf16 [B, N, HC]   (pixel-major for A-fragments)
//   o in [256,512)  -> G  bf16 [B, N, HC]   (pixel-major for B-fragments)
//   o in [512,1024) -> V  bf16 [B, C, N]    (c-major for PV B-fragments)
// ---------------------------------------------------------------------------
__global__ __launch_bounds__(256) void proj_kernel(
    const float* __restrict__ x,
    const float* __restrict__ Wf, const float* __restrict__ bf,
    const float* __restrict__ Wg, const float* __restrict__ bg,
    const float* __restrict__ Wh, const float* __restrict__ bh,
    unsigned short* __restrict__ Fo, unsigned short* __restrict__ Go,
    unsigned short* __restrict__ Vo)
{
    __shared__ float As[16][68];   // [c][o]
    __shared__ float Bs[16][68];   // [c][n]
    const int b  = blockIdx.z;
    const int o0 = blockIdx.y * 64;
    const int n0 = blockIdx.x * 64;
    const int t  = threadIdx.x;
    const int tx = t & 15;          // n micro-tile
    const int ty = t >> 4;          // o micro-tile
    const int ar = t >> 2;          // A-loader row (o)
    const int ac = (t & 3) * 4;     // A-loader col (c)
    const int br = t >> 4;          // B-loader row (c)
    const int bn = (t & 15) * 4;    // B-loader col (n)
    const float* xb = x + (size_t)b * CH * NPIX;

    const int o_l = o0 + ar;
    const float* wrow;
    if (o_l < HCH)          wrow = Wf + (size_t)o_l * CH;
    else if (o_l < 2 * HCH) wrow = Wg + (size_t)(o_l - HCH) * CH;
    else                    wrow = Wh + (size_t)(o_l - 2 * HCH) * CH;

    float acc[4][4];
    #pragma unroll
    for (int i = 0; i < 4; ++i)
        #pragma unroll
        for (int j = 0; j < 4; ++j) acc[i][j] = 0.f;

    for (int c0 = 0; c0 < CH; c0 += 16) {
        float4 a4 = *(const float4*)(wrow + c0 + ac);
        float4 b4 = *(const float4*)(xb + (size_t)(c0 + br) * NPIX + n0 + bn);
        __syncthreads();
        As[ac + 0][ar] = a4.x;
        As[ac + 1][ar] = a4.y;
        As[ac + 2][ar] = a4.z;
        As[ac + 3][ar] = a4.w;
        *(float4*)&Bs[br][bn] = b4;
        __syncthreads();
        #pragma unroll
        for (int cc = 0; cc < 16; ++cc) {
            float4 av = *(const float4*)&As[cc][ty * 4];
            float4 bv = *(const float4*)&Bs[cc][tx * 4];
            const float a_[4] = {av.x, av.y, av.z, av.w};
            const float b_[4] = {bv.x, bv.y, bv.z, bv.w};
            #pragma unroll
            for (int i = 0; i < 4; ++i)
                #pragma unroll
                for (int j = 0; j < 4; ++j)
                    acc[i][j] += a_[i] * b_[j];
        }
    }

    float bias_i[4];
    #pragma unroll
    for (int i = 0; i < 4; ++i) {
        const int o = o0 + ty * 4 + i;
        if (o < HCH)          bias_i[i] = bf[o];
        else if (o < 2 * HCH) bias_i[i] = bg[o - HCH];
        else                  bias_i[i] = bh[o - 2 * HCH];
    }

    if (o0 < 2 * HCH) {
        // F or G: [b][n][o] bf16, pack 4 consecutive o per store
        unsigned short* dst = (o0 < HCH) ? Fo : Go;
        const int ob = (o0 < HCH) ? o0 : (o0 - HCH);
        #pragma unroll
        for (int j = 0; j < 4; ++j) {
            const int n = n0 + tx * 4 + j;
            ushort4 u;
            u.x = f2bf(acc[0][j] + bias_i[0]);
            u.y = f2bf(acc[1][j] + bias_i[1]);
            u.z = f2bf(acc[2][j] + bias_i[2]);
            u.w = f2bf(acc[3][j] + bias_i[3]);
            *(ushort4*)&dst[((size_t)b * NPIX + n) * HCH + ob + ty * 4] = u;
        }
    } else {
        // V: [b][c][n] bf16, pack 4 consecutive n per store
        const int cb = o0 - 2 * HCH;
        #pragma unroll
        for (int i = 0; i < 4; ++i) {
            ushort4 u;
            u.x = f2bf(acc[i][0] + bias_i[i]);
            u.y = f2bf(acc[i][1] + bias_i[i]);
            u.z = f2bf(acc[i][2] + bias_i[i]);
            u.w = f2bf(acc[i][3] + bias_i[i]);
            *(ushort4*)&Vo[((size_t)b * CH + cb + ty * 4 + i) * NPIX + n0 + tx * 4] = u;
        }
    }
}

// ---------------------------------------------------------------------------
// Stats pass (MFMA): per block 32 q-rows, sweep 4096 keys. S = Fq·G^T,
// rowsum of exp(S) with m=0 (|S|<~20, fp32-safe). Output rowlinv = 1/l.
// 4 waves: wave w owns k-substrip w*16 of each 64-wide k-tile.
// ---------------------------------------------------------------------------
__global__ __launch_bounds__(256, 2) void stats_kernel(
    const unsigned short* __restrict__ F, const unsigned short* __restrict__ G,
    float* __restrict__ rowlinv)
{
    __shared__ unsigned short Fq[32][264];   // +8 pad, row 528 B
    __shared__ float red[4][32];
    const int b    = blockIdx.y;
    const int q0   = blockIdx.x * 32;
    const int t    = threadIdx.x;
    const int wave = t >> 6;
    const int lane = t & 63;
    const int quad = lane >> 4;
    const int l16  = lane & 15;

    const unsigned short* Fb = F + ((size_t)b * NPIX + q0) * HCH;
    for (int idx = t; idx < 1024; idx += 256) {
        const int q = idx >> 5, ck = (idx & 31) * 8;
        *(uint4*)&Fq[q][ck] = *(const uint4*)(Fb + q * HCH + ck);
    }
    __syncthreads();

    bf16x8 afrag[2][8];
    #pragma unroll
    for (int qs = 0; qs < 2; ++qs)
        #pragma unroll
        for (int st = 0; st < 8; ++st)
            afrag[qs][st] = *(const bf16x8*)&Fq[qs * 16 + l16][st * 32 + quad * 8];

    float lsum[8];
    #pragma unroll
    for (int r = 0; r < 8; ++r) lsum[r] = 0.f;

    const unsigned short* Gb = G + (size_t)b * NPIX * HCH;
    for (int k0 = 0; k0 < NPIX; k0 += 64) {
        const unsigned short* gp = Gb + (size_t)(k0 + wave * 16 + l16) * HCH + quad * 8;
        f32x4 s0 = {0.f, 0.f, 0.f, 0.f}, s1 = {0.f, 0.f, 0.f, 0.f};
        #pragma unroll
        for (int st = 0; st < 8; ++st) {
            bf16x8 bfrag = *(const bf16x8*)(gp + st * 32);
            s0 = __builtin_amdgcn_mfma_f32_16x16x32_bf16(afrag[0][st], bfrag, s0, 0, 0, 0);
            s1 = __builtin_amdgcn_mfma_f32_16x16x32_bf16(afrag[1][st], bfrag, s1, 0, 0, 0);
        }
        #pragma unroll
        for (int r = 0; r < 4; ++r) {
            lsum[r]     += exp2f(L2E * s0[r]);
            lsum[4 + r] += exp2f(L2E * s1[r]);
        }
    }

    // merge over the 16 lanes that share rows (same quad group)
    #pragma unroll
    for (int d = 1; d < 16; d <<= 1)
        #pragma unroll
        for (int r = 0; r < 8; ++r) lsum[r] += __shfl_xor(lsum[r], d, 64);

    if (l16 == 0) {
        #pragma unroll
        for (int r = 0; r < 4; ++r) {
            red[wave][quad * 4 + r]      = lsum[r];
            red[wave][16 + quad * 4 + r] = lsum[4 + r];
        }
    }
    __syncthreads();
    if (t < 32) {
        const float l = red[0][t] + red[1][t] + red[2][t] + red[3][t];
        rowlinv[(size_t)b * NPIX + q0 + t] = 1.0f / l;
    }
}

// ---------------------------------------------------------------------------
// Apply pass (MFMA): recompute S strip, P = exp(S)*linv (final), then
// O += P·V with O = 32q x 128c fp32 per wave; attention colsums via
// shuffles + one atomicAdd per col per wave per k-tile.
// ---------------------------------------------------------------------------
__global__ __launch_bounds__(256, 2) void apply_kernel(
    const unsigned short* __restrict__ F, const unsigned short* __restrict__ G,
    const unsigned short* __restrict__ V, const float* __restrict__ rowlinv,
    float* __restrict__ outres, float* __restrict__ attnacc)
{
    __shared__ unsigned short Fq[32][264];
    __shared__ unsigned short P[32][72];     // +8 pad, row 144 B
    const int b    = blockIdx.y;
    const int q0   = blockIdx.x * 32;
    const int t    = threadIdx.x;
    const int wave = t >> 6;
    const int lane = t & 63;
    const int quad = lane >> 4;
    const int l16  = lane & 15;

    const unsigned short* Fb = F + ((size_t)b * NPIX + q0) * HCH;
    for (int idx = t; idx < 1024; idx += 256) {
        const int q = idx >> 5, ck = (idx & 31) * 8;
        *(uint4*)&Fq[q][ck] = *(const uint4*)(Fb + q * HCH + ck);
    }
    __syncthreads();

    bf16x8 afrag[2][8];
    #pragma unroll
    for (int qs = 0; qs < 2; ++qs)
        #pragma unroll
        for (int st = 0; st < 8; ++st)
            afrag[qs][st] = *(const bf16x8*)&Fq[qs * 16 + l16][st * 32 + quad * 8];

    float linv[8];
    const float* lb = rowlinv + (size_t)b * NPIX + q0;
    #pragma unroll
    for (int r = 0; r < 4; ++r) {
        linv[r]     = lb[quad * 4 + r];
        linv[4 + r] = lb[16 + quad * 4 + r];
    }

    f32x4 O[2][8];
    #pragma unroll
    for (int qs = 0; qs < 2; ++qs)
        #pragma unroll
        for (int ct = 0; ct < 8; ++ct)
            O[qs][ct] = (f32x4){0.f, 0.f, 0.f, 0.f};

    const unsigned short* Gb = G + (size_t)b * NPIX * HCH;
    const unsigned short* Vb = V + (size_t)b * CH * NPIX;
    const int cbase = wave * 128;
    const int col   = wave * 16 + l16;

    for (int k0 = 0; k0 < NPIX; k0 += 64) {
        // S strip: 32q x 16k for this wave
        const unsigned short* gp = Gb + (size_t)(k0 + col) * HCH + quad * 8;
        f32x4 s0 = {0.f, 0.f, 0.f, 0.f}, s1 = {0.f, 0.f, 0.f, 0.f};
        #pragma unroll
        for (int st = 0; st < 8; ++st) {
            bf16x8 bfrag = *(const bf16x8*)(gp + st * 32);
            s0 = __builtin_amdgcn_mfma_f32_16x16x32_bf16(afrag[0][st], bfrag, s0, 0, 0, 0);
            s1 = __builtin_amdgcn_mfma_f32_16x16x32_bf16(afrag[1][st], bfrag, s1, 0, 0, 0);
        }
        float p[8];
        #pragma unroll
        for (int r = 0; r < 4; ++r) {
            p[r]     = exp2f(L2E * s0[r]) * linv[r];
            p[4 + r] = exp2f(L2E * s1[r]) * linv[4 + r];
        }

        __syncthreads();   // previous tile's P fragment reads complete
        #pragma unroll
        for (int r = 0; r < 4; ++r) {
            P[quad * 4 + r][col]      = f2bf(p[r]);
            P[16 + quad * 4 + r][col] = f2bf(p[4 + r]);
        }
        __syncthreads();

        // attention colsum: sum over 32 q-rows of this col
        float cs = p[0] + p[1] + p[2] + p[3] + p[4] + p[5] + p[6] + p[7];
        cs += __shfl_xor(cs, 16, 64);
        cs += __shfl_xor(cs, 32, 64);
        if (quad == 0) atomicAdd(&attnacc[(size_t)b * NPIX + k0 + col], cs);

        // P A-fragments (inner K = 64 keys -> 2 steps)
        bf16x8 pa[2][2];
        #pragma unroll
        for (int qs = 0; qs < 2; ++qs)
            #pragma unroll
            for (int ks = 0; ks < 2; ++ks)
                pa[qs][ks] = *(const bf16x8*)&P[qs * 16 + l16][ks * 32 + quad * 8];

        // PV: V B-fragments straight from global [C, N]
        const unsigned short* vp = Vb + (size_t)(cbase + l16) * NPIX + k0 + quad * 8;
        #pragma unroll
        for (int ct = 0; ct < 8; ++ct) {
            #pragma unroll
            for (int ks = 0; ks < 2; ++ks) {
                bf16x8 vb = *(const bf16x8*)(vp + (size_t)ct * 16 * NPIX + ks * 32);
                O[0][ct] = __builtin_amdgcn_mfma_f32_16x16x32_bf16(pa[0][ks], vb, O[0][ct], 0, 0, 0);
                O[1][ct] = __builtin_amdgcn_mfma_f32_16x16x32_bf16(pa[1][ks], vb, O[1][ct], 0, 0, 0);
            }
        }
    }

    // epilogue: D-layout row = q offset (quad*4+reg), col = c offset (l16)
    #pragma unroll
    for (int qs = 0; qs < 2; ++qs) {
        #pragma unroll
        for (int ct = 0; ct < 8; ++ct) {
            const int c = cbase + ct * 16 + l16;
            *(f32x4*)&outres[((size_t)b * CH + c) * NPIX + q0 + qs * 16 + quad * 4] = O[qs][ct];
        }
    }
}

__global__ __launch_bounds__(256) void attn_fin_kernel(
    const float* __restrict__ acc, float* __restrict__ outa)
{
    const int i = blockIdx.x * 256 + threadIdx.x;
    if (i < BATCH * NPIX) outa[i] = acc[i] * (1.0f / (float)NPIX);
}

extern "C" void kernel_launch(void* const* d_in, const int* in_sizes, int n_in,
                              void* d_out, int out_size, void* d_ws, size_t ws_size,
                              hipStream_t stream)
{
    (void)in_sizes; (void)n_in; (void)out_size; (void)ws_size;
    const float* x  = (const float*)d_in[0];
    const float* Wf = (const float*)d_in[1];
    const float* bf = (const float*)d_in[2];
    const float* Wg = (const float*)d_in[3];
    const float* bg = (const float*)d_in[4];
    const float* Wh = (const float*)d_in[5];
    const float* bh = (const float*)d_in[6];
    float* out = (float*)d_out;

    unsigned short* F = (unsigned short*)d_ws;                       // 4*4096*256
    unsigned short* G = F + (size_t)BATCH * NPIX * HCH;              // 4*4096*256
    unsigned short* V = G + (size_t)BATCH * NPIX * HCH;              // 4*512*4096
    float* rowlinv = (float*)(V + (size_t)BATCH * CH * NPIX);        // 4*4096
    float* attnacc = rowlinv + (size_t)BATCH * NPIX;                 // 4*4096

    hipMemsetAsync(attnacc, 0, (size_t)BATCH * NPIX * sizeof(float), stream);

    dim3 g1(64, 16, BATCH);
    proj_kernel<<<g1, 256, 0, stream>>>(x, Wf, bf, Wg, bg, Wh, bh, F, G, V);

    dim3 g2(NPIX / 32, BATCH);
    stats_kernel<<<g2, 256, 0, stream>>>(F, G, rowlinv);
    apply_kernel<<<g2, 256, 0, stream>>>(F, G, V, rowlinv, out, attnacc);

    attn_fin_kernel<<<BATCH * NPIX / 256, 256, 0, stream>>>(
        attnacc, out + (size_t)BATCH * CH * NPIX);
}

// Round 4
// 666.149 us; speedup vs baseline: 25.2291x; 1.2774x over previous
//
#include <hip/hip_runtime.h>
#include <cmath>

#define BATCH 4
#define CH    512
#define HCH   256
#define NPIX  4096
#define L2E   1.44269504088896340736f

typedef __attribute__((ext_vector_type(8))) short bf16x8;
typedef __attribute__((ext_vector_type(4))) float f32x4;

#define MFMA16(a, b, c) __builtin_amdgcn_mfma_f32_16x16x32_bf16((a), (b), (c), 0, 0, 0)

__device__ __forceinline__ unsigned short f2bf(float f) {
    unsigned int u = __float_as_uint(f);
    return (unsigned short)((u + 0x7fffu + ((u >> 16) & 1u)) >> 16);
}
__device__ __forceinline__ ushort4 pack4(float a, float b, float c, float d) {
    ushort4 u; u.x = f2bf(a); u.y = f2bf(b); u.z = f2bf(c); u.w = f2bf(d); return u;
}

// ---------------------------------------------------------------------------
// Wc[1024][512] bf16 = concat(Wf, Wg, Wh) rows, K-contiguous (A/B-frag ready).
// ---------------------------------------------------------------------------
__global__ __launch_bounds__(256) void convert_w_kernel(
    const float* __restrict__ Wf, const float* __restrict__ Wg,
    const float* __restrict__ Wh, unsigned short* __restrict__ Wc)
{
    const int idx = blockIdx.x * 256 + threadIdx.x;    // 131072 float4s
    const int o  = idx >> 7;
    const int c4 = (idx & 127) * 4;
    const float* src = (o < HCH)     ? (Wf + (size_t)o * CH + c4)
                     : (o < 2 * HCH) ? (Wg + (size_t)(o - HCH) * CH + c4)
                                     : (Wh + (size_t)(o - 2 * HCH) * CH + c4);
    float4 v = *(const float4*)src;
    *(ushort4*)&Wc[(size_t)o * CH + c4] = pack4(v.x, v.y, v.z, v.w);
}

// ---------------------------------------------------------------------------
// X' swizzle: x fp32 [b][512][4096] -> bf16 [b][cb=16][n=4096][co=32].
// Fragment load (lane l16 -> row, quad*8 -> k-offset) becomes 1KiB contiguous.
// ---------------------------------------------------------------------------
__global__ __launch_bounds__(256) void convert_x_kernel(
    const float* __restrict__ x, unsigned short* __restrict__ Xp)
{
    __shared__ unsigned short Lt[64][40];   // [n][c], pitch 40 (16B-aligned rows)
    const int b  = blockIdx.z;
    const int cb = blockIdx.y;
    const int n0 = blockIdx.x * 64;
    const int t  = threadIdx.x;
    const int cr = t >> 4;
    const int f4 = t & 15;
    #pragma unroll
    for (int p = 0; p < 2; ++p) {
        const int c = p * 16 + cr;
        float4 v = *(const float4*)(x + ((size_t)b * CH + cb * 32 + c) * NPIX + n0 + f4 * 4);
        Lt[f4 * 4 + 0][c] = f2bf(v.x);
        Lt[f4 * 4 + 1][c] = f2bf(v.y);
        Lt[f4 * 4 + 2][c] = f2bf(v.z);
        Lt[f4 * 4 + 3][c] = f2bf(v.w);
    }
    __syncthreads();
    const int n  = t >> 2;
    const int ch = t & 3;
    uint4 u = *(const uint4*)&Lt[n][ch * 8];
    *(uint4*)&Xp[((size_t)b * 16 + cb) * (NPIX * 32) + (size_t)(n0 + n) * 32 + ch * 8] = u;
}

// ---------------------------------------------------------------------------
// proj F/G: D[o][n] = Wc[o,:]·x[:,n] + bias.  o0 in {0,128}: F [b][n][256];
// o0 in {256,384}: G' [b][c/32][n][c%32].  Block: 128o x 128n, wave = 32o.
// ---------------------------------------------------------------------------
__global__ __launch_bounds__(256, 2) void proj_fg_kernel(
    const unsigned short* __restrict__ Wc, const unsigned short* __restrict__ Xp,
    const float* __restrict__ bf, const float* __restrict__ bg,
    unsigned short* __restrict__ F, unsigned short* __restrict__ G)
{
    const int b  = blockIdx.z;
    const int n0 = blockIdx.x * 128;
    const int o0 = blockIdx.y * 128;
    const int t  = threadIdx.x;
    const int wave = t >> 6, lane = t & 63, quad = lane >> 4, l16 = lane & 15;
    const int ow = o0 + wave * 32;

    f32x4 acc[2][8];
    #pragma unroll
    for (int ms = 0; ms < 2; ++ms)
        #pragma unroll
        for (int ns = 0; ns < 8; ++ns) acc[ms][ns] = (f32x4){0.f, 0.f, 0.f, 0.f};

    const unsigned short* xb = Xp + (size_t)b * 16 * (NPIX * 32);
    for (int st = 0; st < 16; ++st) {
        bf16x8 a0 = *(const bf16x8*)&Wc[(size_t)(ow + l16) * CH + st * 32 + quad * 8];
        bf16x8 a1 = *(const bf16x8*)&Wc[(size_t)(ow + 16 + l16) * CH + st * 32 + quad * 8];
        const unsigned short* xs = xb + (size_t)st * (NPIX * 32) + quad * 8;
        #pragma unroll
        for (int ns = 0; ns < 8; ++ns) {
            bf16x8 bb = *(const bf16x8*)(xs + (size_t)(n0 + ns * 16 + l16) * 32);
            acc[0][ns] = MFMA16(a0, bb, acc[0][ns]);
            acc[1][ns] = MFMA16(a1, bb, acc[1][ns]);
        }
    }

    const int orow = quad * 4;
    #pragma unroll
    for (int ms = 0; ms < 2; ++ms) {
        const int ob = ow + ms * 16 + orow;          // o base for regs r=0..3
        float bias[4];
        #pragma unroll
        for (int r = 0; r < 4; ++r)
            bias[r] = (o0 < HCH) ? bf[ob + r] : bg[ob + r - HCH];
        #pragma unroll
        for (int ns = 0; ns < 8; ++ns) {
            const int n = n0 + ns * 16 + l16;
            ushort4 u = pack4(acc[ms][ns][0] + bias[0], acc[ms][ns][1] + bias[1],
                              acc[ms][ns][2] + bias[2], acc[ms][ns][3] + bias[3]);
            if (o0 < HCH) {
                *(ushort4*)&F[((size_t)b * NPIX + n) * HCH + ob] = u;
            } else {
                const int og = ob - HCH;
                const int cb = og >> 5, co = og & 31;
                *(ushort4*)&G[((size_t)b * 8 + cb) * (NPIX * 32) + (size_t)n * 32 + co] = u;
            }
        }
    }
}

// ---------------------------------------------------------------------------
// proj V: D[pixel][c] = x[:,pixel]·Wh[c,:] + bh  ->  V' [b][k/32][c][k%32].
// Block: 128pix x 128c, wave = 32 pixels.
// ---------------------------------------------------------------------------
__global__ __launch_bounds__(256, 2) void proj_v_kernel(
    const unsigned short* __restrict__ Wc, const unsigned short* __restrict__ Xp,
    const float* __restrict__ bh, unsigned short* __restrict__ V)
{
    const int b  = blockIdx.z;
    const int c0 = blockIdx.x * 128;
    const int p0 = blockIdx.y * 128;
    const int t  = threadIdx.x;
    const int wave = t >> 6, lane = t & 63, quad = lane >> 4, l16 = lane & 15;
    const int pw = p0 + wave * 32;

    f32x4 acc[2][8];
    #pragma unroll
    for (int ms = 0; ms < 2; ++ms)
        #pragma unroll
        for (int ns = 0; ns < 8; ++ns) acc[ms][ns] = (f32x4){0.f, 0.f, 0.f, 0.f};

    const unsigned short* xb = Xp + (size_t)b * 16 * (NPIX * 32);
    for (int st = 0; st < 16; ++st) {
        const unsigned short* xs = xb + (size_t)st * (NPIX * 32) + quad * 8;
        bf16x8 a0 = *(const bf16x8*)(xs + (size_t)(pw + l16) * 32);
        bf16x8 a1 = *(const bf16x8*)(xs + (size_t)(pw + 16 + l16) * 32);
        #pragma unroll
        for (int ns = 0; ns < 8; ++ns) {
            bf16x8 bb = *(const bf16x8*)&Wc[(size_t)(2 * HCH + c0 + ns * 16 + l16) * CH + st * 32 + quad * 8];
            acc[0][ns] = MFMA16(a0, bb, acc[0][ns]);
            acc[1][ns] = MFMA16(a1, bb, acc[1][ns]);
        }
    }

    float biasv[8];
    #pragma unroll
    for (int ns = 0; ns < 8; ++ns) biasv[ns] = bh[c0 + ns * 16 + l16];

    const int kb = pw >> 5;
    const int ko0 = quad * 4;
    #pragma unroll
    for (int ms = 0; ms < 2; ++ms) {
        #pragma unroll
        for (int ns = 0; ns < 8; ++ns) {
            const int c = c0 + ns * 16 + l16;
            ushort4 u = pack4(acc[ms][ns][0] + biasv[ns], acc[ms][ns][1] + biasv[ns],
                              acc[ms][ns][2] + biasv[ns], acc[ms][ns][3] + biasv[ns]);
            *(ushort4*)&V[((size_t)b * 128 + kb) * (CH * 32) + (size_t)c * 32 + ms * 16 + ko0] = u;
        }
    }
}

// ---------------------------------------------------------------------------
// Stats: partial softmax denominators (m=0).  Block = 32q x 2048 keys (khalf),
// wave owns 32-key strip per 128-iter.  atomicAdd partials into rowl.
// ---------------------------------------------------------------------------
__global__ __launch_bounds__(256, 2) void stats_kernel(
    const unsigned short* __restrict__ F, const unsigned short* __restrict__ G,
    float* __restrict__ rowl)
{
    const int b  = blockIdx.z;
    const int kh = blockIdx.y;
    const int q0 = blockIdx.x * 32;
    const int t  = threadIdx.x;
    const int wave = t >> 6, lane = t & 63, quad = lane >> 4, l16 = lane & 15;

    bf16x8 af[2][8];
    #pragma unroll
    for (int qs = 0; qs < 2; ++qs)
        #pragma unroll
        for (int st = 0; st < 8; ++st)
            af[qs][st] = *(const bf16x8*)&F[((size_t)b * NPIX + q0 + qs * 16 + l16) * HCH + st * 32 + quad * 8];

    float ls[8];
    #pragma unroll
    for (int i = 0; i < 8; ++i) ls[i] = 0.f;

    const unsigned short* Gb = G + (size_t)b * 8 * (NPIX * 32);
    const int kend = kh * 2048 + 2048;
    for (int k0 = kh * 2048; k0 < kend; k0 += 128) {
        const int kk = k0 + wave * 32;
        f32x4 s[2][2];
        #pragma unroll
        for (int qs = 0; qs < 2; ++qs)
            #pragma unroll
            for (int ks = 0; ks < 2; ++ks) s[qs][ks] = (f32x4){0.f, 0.f, 0.f, 0.f};
        #pragma unroll
        for (int st = 0; st < 8; ++st) {
            const unsigned short* gs = Gb + (size_t)st * (NPIX * 32) + quad * 8;
            bf16x8 b0 = *(const bf16x8*)(gs + (size_t)(kk + l16) * 32);
            bf16x8 b1 = *(const bf16x8*)(gs + (size_t)(kk + 16 + l16) * 32);
            s[0][0] = MFMA16(af[0][st], b0, s[0][0]);
            s[1][0] = MFMA16(af[1][st], b0, s[1][0]);
            s[0][1] = MFMA16(af[0][st], b1, s[0][1]);
            s[1][1] = MFMA16(af[1][st], b1, s[1][1]);
        }
        #pragma unroll
        for (int qs = 0; qs < 2; ++qs)
            #pragma unroll
            for (int r = 0; r < 4; ++r)
                ls[qs * 4 + r] += exp2f(L2E * s[qs][0][r]) + exp2f(L2E * s[qs][1][r]);
    }

    #pragma unroll
    for (int d = 1; d < 16; d <<= 1)
        #pragma unroll
        for (int i = 0; i < 8; ++i) ls[i] += __shfl_xor(ls[i], d, 64);

    if (l16 == 0) {
        #pragma unroll
        for (int qs = 0; qs < 2; ++qs)
            #pragma unroll
            for (int r = 0; r < 4; ++r)
                atomicAdd(&rowl[(size_t)b * NPIX + q0 + qs * 16 + quad * 4 + r], ls[qs * 4 + r]);
    }
}

// ---------------------------------------------------------------------------
// Apply: recompute S strip (wave = 32 keys of 128-key block tile),
// P = exp(S)/l final -> LDS, colsums -> atomics, O += P·V (wave = 128 c).
// ---------------------------------------------------------------------------
__global__ __launch_bounds__(256, 2) void apply_kernel(
    const unsigned short* __restrict__ F, const unsigned short* __restrict__ G,
    const unsigned short* __restrict__ V, const float* __restrict__ rowl,
    float* __restrict__ outres, float* __restrict__ attnacc)
{
    __shared__ unsigned short P[32][136];   // pitch 136: 16B-aligned rows
    const int b  = blockIdx.y;
    const int q0 = blockIdx.x * 32;
    const int t  = threadIdx.x;
    const int wave = t >> 6, lane = t & 63, quad = lane >> 4, l16 = lane & 15;

    bf16x8 af[2][8];
    #pragma unroll
    for (int qs = 0; qs < 2; ++qs)
        #pragma unroll
        for (int st = 0; st < 8; ++st)
            af[qs][st] = *(const bf16x8*)&F[((size_t)b * NPIX + q0 + qs * 16 + l16) * HCH + st * 32 + quad * 8];

    float linv[2][4];
    #pragma unroll
    for (int qs = 0; qs < 2; ++qs)
        #pragma unroll
        for (int r = 0; r < 4; ++r)
            linv[qs][r] = 1.0f / rowl[(size_t)b * NPIX + q0 + qs * 16 + quad * 4 + r];

    f32x4 O[2][8];
    #pragma unroll
    for (int qs = 0; qs < 2; ++qs)
        #pragma unroll
        for (int ct = 0; ct < 8; ++ct) O[qs][ct] = (f32x4){0.f, 0.f, 0.f, 0.f};

    const unsigned short* Gb = G + (size_t)b * 8 * (NPIX * 32);
    const unsigned short* Vb = V + (size_t)b * 128 * (CH * 32);
    const int cb0 = wave * 128;

    for (int k0 = 0; k0 < NPIX; k0 += 128) {
        const int kk = k0 + wave * 32;
        f32x4 s[2][2];
        #pragma unroll
        for (int qs = 0; qs < 2; ++qs)
            #pragma unroll
            for (int ks = 0; ks < 2; ++ks) s[qs][ks] = (f32x4){0.f, 0.f, 0.f, 0.f};
        #pragma unroll
        for (int st = 0; st < 8; ++st) {
            const unsigned short* gs = Gb + (size_t)st * (NPIX * 32) + quad * 8;
            bf16x8 b0 = *(const bf16x8*)(gs + (size_t)(kk + l16) * 32);
            bf16x8 b1 = *(const bf16x8*)(gs + (size_t)(kk + 16 + l16) * 32);
            s[0][0] = MFMA16(af[0][st], b0, s[0][0]);
            s[1][0] = MFMA16(af[1][st], b0, s[1][0]);
            s[0][1] = MFMA16(af[0][st], b1, s[0][1]);
            s[1][1] = MFMA16(af[1][st], b1, s[1][1]);
        }

        float p[2][2][4];
        #pragma unroll
        for (int qs = 0; qs < 2; ++qs)
            #pragma unroll
            for (int ks = 0; ks < 2; ++ks)
                #pragma unroll
                for (int r = 0; r < 4; ++r)
                    p[qs][ks][r] = exp2f(L2E * s[qs][ks][r]) * linv[qs][r];

        __syncthreads();   // prior iteration's P consumers done
        #pragma unroll
        for (int qs = 0; qs < 2; ++qs)
            #pragma unroll
            for (int ks = 0; ks < 2; ++ks)
                #pragma unroll
                for (int r = 0; r < 4; ++r)
                    P[qs * 16 + quad * 4 + r][wave * 32 + ks * 16 + l16] = f2bf(p[qs][ks][r]);
        __syncthreads();

        // attention column sums (final P, no rescale needed)
        #pragma unroll
        for (int ks = 0; ks < 2; ++ks) {
            float cs = p[0][ks][0] + p[0][ks][1] + p[0][ks][2] + p[0][ks][3]
                     + p[1][ks][0] + p[1][ks][1] + p[1][ks][2] + p[1][ks][3];
            cs += __shfl_xor(cs, 16, 64);
            cs += __shfl_xor(cs, 32, 64);
            if (quad == 0)
                atomicAdd(&attnacc[(size_t)b * NPIX + kk + ks * 16 + l16], cs);
        }

        // PV over the block's 128-key tile, wave's 128-c strip
        #pragma unroll
        for (int ks = 0; ks < 4; ++ks) {
            bf16x8 pa0 = *(const bf16x8*)&P[l16][ks * 32 + quad * 8];
            bf16x8 pa1 = *(const bf16x8*)&P[16 + l16][ks * 32 + quad * 8];
            const unsigned short* vs = Vb + ((size_t)(k0 >> 5) + ks) * (CH * 32) + quad * 8;
            #pragma unroll
            for (int ct = 0; ct < 8; ++ct) {
                bf16x8 vb = *(const bf16x8*)(vs + (size_t)(cb0 + ct * 16 + l16) * 32);
                O[0][ct] = MFMA16(pa0, vb, O[0][ct]);
                O[1][ct] = MFMA16(pa1, vb, O[1][ct]);
            }
        }
    }

    #pragma unroll
    for (int qs = 0; qs < 2; ++qs) {
        #pragma unroll
        for (int ct = 0; ct < 8; ++ct) {
            const int c = cb0 + ct * 16 + l16;
            *(f32x4*)&outres[((size_t)b * CH + c) * NPIX + q0 + qs * 16 + quad * 4] = O[qs][ct];
        }
    }
}

__global__ __launch_bounds__(256) void attn_fin_kernel(
    const float* __restrict__ acc, float* __restrict__ outa)
{
    const int i = blockIdx.x * 256 + threadIdx.x;
    if (i < BATCH * NPIX) outa[i] = acc[i] * (1.0f / (float)NPIX);
}

extern "C" void kernel_launch(void* const* d_in, const int* in_sizes, int n_in,
                              void* d_out, int out_size, void* d_ws, size_t ws_size,
                              hipStream_t stream)
{
    (void)in_sizes; (void)n_in; (void)out_size; (void)ws_size;
    const float* x  = (const float*)d_in[0];
    const float* Wf = (const float*)d_in[1];
    const float* bf = (const float*)d_in[2];
    const float* Wg = (const float*)d_in[3];
    const float* bg = (const float*)d_in[4];
    const float* Wh = (const float*)d_in[5];
    const float* bh = (const float*)d_in[6];
    float* out = (float*)d_out;

    unsigned short* Xp = (unsigned short*)d_ws;                      // 4*16*4096*32
    unsigned short* Wc = Xp + (size_t)BATCH * 16 * NPIX * 32;        // 1024*512
    unsigned short* F  = Wc + (size_t)1024 * CH;                     // 4*4096*256
    unsigned short* G  = F + (size_t)BATCH * NPIX * HCH;             // 4*8*4096*32
    unsigned short* V  = G + (size_t)BATCH * NPIX * HCH;             // 4*128*512*32
    float* rowl    = (float*)(V + (size_t)BATCH * NPIX * CH);        // 4*4096
    float* attnacc = rowl + (size_t)BATCH * NPIX;                    // 4*4096

    hipMemsetAsync(rowl, 0, (size_t)2 * BATCH * NPIX * sizeof(float), stream);

    convert_w_kernel<<<512, 256, 0, stream>>>(Wf, Wg, Wh, Wc);
    convert_x_kernel<<<dim3(NPIX / 64, 16, BATCH), 256, 0, stream>>>(x, Xp);

    proj_fg_kernel<<<dim3(NPIX / 128, 4, BATCH), 256, 0, stream>>>(Wc, Xp, bf, bg, F, G);
    proj_v_kernel<<<dim3(4, NPIX / 128, BATCH), 256, 0, stream>>>(Wc, Xp, bh, V);

    stats_kernel<<<dim3(NPIX / 32, 2, BATCH), 256, 0, stream>>>(F, G, rowl);
    apply_kernel<<<dim3(NPIX / 32, BATCH), 256, 0, stream>>>(F, G, V, rowl, out, attnacc);

    attn_fin_kernel<<<BATCH * NPIX / 256, 256, 0, stream>>>(
        attnacc, out + (size_t)BATCH * CH * NPIX);
}

// Round 5
// 548.065 us; speedup vs baseline: 30.6648x; 1.2155x over previous
//
#include <hip/hip_runtime.h>
#include <cmath>

#define BATCH 4
#define CH    512
#define HCH   256
#define NPIX  4096
#define L2E   1.44269504088896340736f

typedef __attribute__((ext_vector_type(8))) short bf16x8;
typedef __attribute__((ext_vector_type(4))) float f32x4;

#define MFMA16(a, b, c) __builtin_amdgcn_mfma_f32_16x16x32_bf16((a), (b), (c), 0, 0, 0)

__device__ __forceinline__ unsigned short f2bf(float f) {
    unsigned int u = __float_as_uint(f);
    return (unsigned short)((u + 0x7fffu + ((u >> 16) & 1u)) >> 16);
}
__device__ __forceinline__ ushort4 pack4(float a, float b, float c, float d) {
    ushort4 u; u.x = f2bf(a); u.y = f2bf(b); u.z = f2bf(c); u.w = f2bf(d); return u;
}

// ---------------------------------------------------------------------------
// Wc[1024][512] bf16 = concat(Wf, Wg, Wh) rows, K-contiguous.
// ---------------------------------------------------------------------------
__global__ __launch_bounds__(256) void convert_w_kernel(
    const float* __restrict__ Wf, const float* __restrict__ Wg,
    const float* __restrict__ Wh, unsigned short* __restrict__ Wc)
{
    const int idx = blockIdx.x * 256 + threadIdx.x;
    const int o  = idx >> 7;
    const int c4 = (idx & 127) * 4;
    const float* src = (o < HCH)     ? (Wf + (size_t)o * CH + c4)
                     : (o < 2 * HCH) ? (Wg + (size_t)(o - HCH) * CH + c4)
                                     : (Wh + (size_t)(o - 2 * HCH) * CH + c4);
    float4 v = *(const float4*)src;
    *(ushort4*)&Wc[(size_t)o * CH + c4] = pack4(v.x, v.y, v.z, v.w);
}

// ---------------------------------------------------------------------------
// X' swizzle: x fp32 [b][512][4096] -> bf16 [b][cb=16][n=4096][co=32].
// ---------------------------------------------------------------------------
__global__ __launch_bounds__(256) void convert_x_kernel(
    const float* __restrict__ x, unsigned short* __restrict__ Xp)
{
    __shared__ unsigned short Lt[64][40];
    const int b  = blockIdx.z;
    const int cb = blockIdx.y;
    const int n0 = blockIdx.x * 64;
    const int t  = threadIdx.x;
    const int cr = t >> 4;
    const int f4 = t & 15;
    #pragma unroll
    for (int p = 0; p < 2; ++p) {
        const int c = p * 16 + cr;
        float4 v = *(const float4*)(x + ((size_t)b * CH + cb * 32 + c) * NPIX + n0 + f4 * 4);
        Lt[f4 * 4 + 0][c] = f2bf(v.x);
        Lt[f4 * 4 + 1][c] = f2bf(v.y);
        Lt[f4 * 4 + 2][c] = f2bf(v.z);
        Lt[f4 * 4 + 3][c] = f2bf(v.w);
    }
    __syncthreads();
    const int n  = t >> 2;
    const int ch = t & 3;
    uint4 u = *(const uint4*)&Lt[n][ch * 8];
    *(uint4*)&Xp[((size_t)b * 16 + cb) * (NPIX * 32) + (size_t)(n0 + n) * 32 + ch * 8] = u;
}

// ---------------------------------------------------------------------------
// proj F/G (unchanged from R4)
// ---------------------------------------------------------------------------
__global__ __launch_bounds__(256, 2) void proj_fg_kernel(
    const unsigned short* __restrict__ Wc, const unsigned short* __restrict__ Xp,
    const float* __restrict__ bf, const float* __restrict__ bg,
    unsigned short* __restrict__ F, unsigned short* __restrict__ G)
{
    const int b  = blockIdx.z;
    const int n0 = blockIdx.x * 128;
    const int o0 = blockIdx.y * 128;
    const int t  = threadIdx.x;
    const int wave = t >> 6, lane = t & 63, quad = lane >> 4, l16 = lane & 15;
    const int ow = o0 + wave * 32;

    f32x4 acc[2][8];
    #pragma unroll
    for (int ms = 0; ms < 2; ++ms)
        #pragma unroll
        for (int ns = 0; ns < 8; ++ns) acc[ms][ns] = (f32x4){0.f, 0.f, 0.f, 0.f};

    const unsigned short* xb = Xp + (size_t)b * 16 * (NPIX * 32);
    for (int st = 0; st < 16; ++st) {
        bf16x8 a0 = *(const bf16x8*)&Wc[(size_t)(ow + l16) * CH + st * 32 + quad * 8];
        bf16x8 a1 = *(const bf16x8*)&Wc[(size_t)(ow + 16 + l16) * CH + st * 32 + quad * 8];
        const unsigned short* xs = xb + (size_t)st * (NPIX * 32) + quad * 8;
        #pragma unroll
        for (int ns = 0; ns < 8; ++ns) {
            bf16x8 bb = *(const bf16x8*)(xs + (size_t)(n0 + ns * 16 + l16) * 32);
            acc[0][ns] = MFMA16(a0, bb, acc[0][ns]);
            acc[1][ns] = MFMA16(a1, bb, acc[1][ns]);
        }
    }

    const int orow = quad * 4;
    #pragma unroll
    for (int ms = 0; ms < 2; ++ms) {
        const int ob = ow + ms * 16 + orow;
        float bias[4];
        #pragma unroll
        for (int r = 0; r < 4; ++r)
            bias[r] = (o0 < HCH) ? bf[ob + r] : bg[ob + r - HCH];
        #pragma unroll
        for (int ns = 0; ns < 8; ++ns) {
            const int n = n0 + ns * 16 + l16;
            ushort4 u = pack4(acc[ms][ns][0] + bias[0], acc[ms][ns][1] + bias[1],
                              acc[ms][ns][2] + bias[2], acc[ms][ns][3] + bias[3]);
            if (o0 < HCH) {
                *(ushort4*)&F[((size_t)b * NPIX + n) * HCH + ob] = u;
            } else {
                const int og = ob - HCH;
                const int cb = og >> 5, co = og & 31;
                *(ushort4*)&G[((size_t)b * 8 + cb) * (NPIX * 32) + (size_t)n * 32 + co] = u;
            }
        }
    }
}

// ---------------------------------------------------------------------------
// proj V (unchanged from R4)
// ---------------------------------------------------------------------------
__global__ __launch_bounds__(256, 2) void proj_v_kernel(
    const unsigned short* __restrict__ Wc, const unsigned short* __restrict__ Xp,
    const float* __restrict__ bh, unsigned short* __restrict__ V)
{
    const int b  = blockIdx.z;
    const int c0 = blockIdx.x * 128;
    const int p0 = blockIdx.y * 128;
    const int t  = threadIdx.x;
    const int wave = t >> 6, lane = t & 63, quad = lane >> 4, l16 = lane & 15;
    const int pw = p0 + wave * 32;

    f32x4 acc[2][8];
    #pragma unroll
    for (int ms = 0; ms < 2; ++ms)
        #pragma unroll
        for (int ns = 0; ns < 8; ++ns) acc[ms][ns] = (f32x4){0.f, 0.f, 0.f, 0.f};

    const unsigned short* xb = Xp + (size_t)b * 16 * (NPIX * 32);
    for (int st = 0; st < 16; ++st) {
        const unsigned short* xs = xb + (size_t)st * (NPIX * 32) + quad * 8;
        bf16x8 a0 = *(const bf16x8*)(xs + (size_t)(pw + l16) * 32);
        bf16x8 a1 = *(const bf16x8*)(xs + (size_t)(pw + 16 + l16) * 32);
        #pragma unroll
        for (int ns = 0; ns < 8; ++ns) {
            bf16x8 bb = *(const bf16x8*)&Wc[(size_t)(2 * HCH + c0 + ns * 16 + l16) * CH + st * 32 + quad * 8];
            acc[0][ns] = MFMA16(a0, bb, acc[0][ns]);
            acc[1][ns] = MFMA16(a1, bb, acc[1][ns]);
        }
    }

    float biasv[8];
    #pragma unroll
    for (int ns = 0; ns < 8; ++ns) biasv[ns] = bh[c0 + ns * 16 + l16];

    const int kb = pw >> 5;
    const int ko0 = quad * 4;
    #pragma unroll
    for (int ms = 0; ms < 2; ++ms) {
        #pragma unroll
        for (int ns = 0; ns < 8; ++ns) {
            const int c = c0 + ns * 16 + l16;
            ushort4 u = pack4(acc[ms][ns][0] + biasv[ns], acc[ms][ns][1] + biasv[ns],
                              acc[ms][ns][2] + biasv[ns], acc[ms][ns][3] + biasv[ns]);
            *(ushort4*)&V[((size_t)b * 128 + kb) * (CH * 32) + (size_t)c * 32 + ms * 16 + ko0] = u;
        }
    }
}

// ---------------------------------------------------------------------------
// Stats: 64q per block, 512 thr, XCD-pinned batch. wave=(qh,kw): qh=q-half,
// kw=32-key strip of each 128-key tile. Full k sweep, atomicAdd partials.
// ---------------------------------------------------------------------------
__global__ __launch_bounds__(512, 2) void stats_kernel(
    const unsigned short* __restrict__ F, const unsigned short* __restrict__ G,
    float* __restrict__ rowl)
{
    const int blk = blockIdx.x;
    const int xcd = blk & 7;              // XCD pinning: batch = xcd>>1
    const int b   = xcd >> 1;
    const int qt  = (blk >> 3) | ((xcd & 1) << 5);
    const int q0  = qt * 64;
    const int t    = threadIdx.x;
    const int wave = t >> 6, lane = t & 63, quad = lane >> 4, l16 = lane & 15;
    const int qh = wave >> 2, kw = wave & 3;

    bf16x8 af[2][8];
    #pragma unroll
    for (int qs = 0; qs < 2; ++qs)
        #pragma unroll
        for (int st = 0; st < 8; ++st)
            af[qs][st] = *(const bf16x8*)&F[((size_t)b * NPIX + q0 + qh * 32 + qs * 16 + l16) * HCH + st * 32 + quad * 8];

    float ls[2][4];
    #pragma unroll
    for (int qs = 0; qs < 2; ++qs)
        #pragma unroll
        for (int r = 0; r < 4; ++r) ls[qs][r] = 0.f;

    const unsigned short* Gb = G + (size_t)b * 8 * (NPIX * 32);
    for (int k0 = 0; k0 < NPIX; k0 += 128) {
        const int kk = k0 + kw * 32;
        f32x4 s[2][2];
        #pragma unroll
        for (int qs = 0; qs < 2; ++qs)
            #pragma unroll
            for (int ks = 0; ks < 2; ++ks) s[qs][ks] = (f32x4){0.f, 0.f, 0.f, 0.f};
        #pragma unroll
        for (int st = 0; st < 8; ++st) {
            const unsigned short* gs = Gb + (size_t)st * (NPIX * 32) + quad * 8;
            bf16x8 b0 = *(const bf16x8*)(gs + (size_t)(kk + l16) * 32);
            bf16x8 b1 = *(const bf16x8*)(gs + (size_t)(kk + 16 + l16) * 32);
            s[0][0] = MFMA16(af[0][st], b0, s[0][0]);
            s[1][0] = MFMA16(af[1][st], b0, s[1][0]);
            s[0][1] = MFMA16(af[0][st], b1, s[0][1]);
            s[1][1] = MFMA16(af[1][st], b1, s[1][1]);
        }
        #pragma unroll
        for (int qs = 0; qs < 2; ++qs)
            #pragma unroll
            for (int r = 0; r < 4; ++r)
                ls[qs][r] += exp2f(L2E * s[qs][0][r]) + exp2f(L2E * s[qs][1][r]);
    }

    #pragma unroll
    for (int d = 1; d < 16; d <<= 1)
        #pragma unroll
        for (int qs = 0; qs < 2; ++qs)
            #pragma unroll
            for (int r = 0; r < 4; ++r) ls[qs][r] += __shfl_xor(ls[qs][r], d, 64);

    if (l16 == 0) {
        #pragma unroll
        for (int qs = 0; qs < 2; ++qs)
            #pragma unroll
            for (int r = 0; r < 4; ++r)
                atomicAdd(&rowl[(size_t)b * NPIX + q0 + qh * 32 + qs * 16 + quad * 4 + r], ls[qs][r]);
    }
}

// ---------------------------------------------------------------------------
// Apply: 64q per block, 512 thr, XCD-pinned. QK strips per wave, P via LDS,
// PV with wave-owned 64-c strip. G fragments for next tile prefetched
// before the PV phase to hide QK load latency.
// ---------------------------------------------------------------------------
__global__ __launch_bounds__(512, 2) void apply_kernel(
    const unsigned short* __restrict__ F, const unsigned short* __restrict__ G,
    const unsigned short* __restrict__ V, const float* __restrict__ rowl,
    float* __restrict__ outres, float* __restrict__ attnacc)
{
    __shared__ unsigned short P[64][136];   // 17.4 KB
    const int blk = blockIdx.x;
    const int xcd = blk & 7;
    const int b   = xcd >> 1;
    const int qt  = (blk >> 3) | ((xcd & 1) << 5);
    const int q0  = qt * 64;
    const int t    = threadIdx.x;
    const int wave = t >> 6, lane = t & 63, quad = lane >> 4, l16 = lane & 15;
    const int qh = wave >> 2, kw = wave & 3;
    const int cb0 = wave * 64;

    bf16x8 af[2][8];
    #pragma unroll
    for (int qs = 0; qs < 2; ++qs)
        #pragma unroll
        for (int st = 0; st < 8; ++st)
            af[qs][st] = *(const bf16x8*)&F[((size_t)b * NPIX + q0 + qh * 32 + qs * 16 + l16) * HCH + st * 32 + quad * 8];

    float linv[2][4];
    #pragma unroll
    for (int qs = 0; qs < 2; ++qs)
        #pragma unroll
        for (int r = 0; r < 4; ++r)
            linv[qs][r] = 1.0f / rowl[(size_t)b * NPIX + q0 + qh * 32 + qs * 16 + quad * 4 + r];

    f32x4 O[4][4];
    #pragma unroll
    for (int qs = 0; qs < 4; ++qs)
        #pragma unroll
        for (int ct = 0; ct < 4; ++ct) O[qs][ct] = (f32x4){0.f, 0.f, 0.f, 0.f};

    const unsigned short* Gb = G + (size_t)b * 8 * (NPIX * 32);
    const unsigned short* Vb = V + (size_t)b * 128 * (CH * 32);

    // prefetch G fragments for tile k0=0
    bf16x8 gb[8][2];
    #pragma unroll
    for (int st = 0; st < 8; ++st) {
        const unsigned short* gs = Gb + (size_t)st * (NPIX * 32) + quad * 8;
        gb[st][0] = *(const bf16x8*)(gs + (size_t)(kw * 32 + l16) * 32);
        gb[st][1] = *(const bf16x8*)(gs + (size_t)(kw * 32 + 16 + l16) * 32);
    }

    for (int k0 = 0; k0 < NPIX; k0 += 128) {
        f32x4 s[2][2];
        #pragma unroll
        for (int qs = 0; qs < 2; ++qs)
            #pragma unroll
            for (int ks = 0; ks < 2; ++ks) s[qs][ks] = (f32x4){0.f, 0.f, 0.f, 0.f};
        #pragma unroll
        for (int st = 0; st < 8; ++st) {
            s[0][0] = MFMA16(af[0][st], gb[st][0], s[0][0]);
            s[1][0] = MFMA16(af[1][st], gb[st][0], s[1][0]);
            s[0][1] = MFMA16(af[0][st], gb[st][1], s[0][1]);
            s[1][1] = MFMA16(af[1][st], gb[st][1], s[1][1]);
        }

        float p[2][2][4];
        #pragma unroll
        for (int qs = 0; qs < 2; ++qs)
            #pragma unroll
            for (int ks = 0; ks < 2; ++ks)
                #pragma unroll
                for (int r = 0; r < 4; ++r)
                    p[qs][ks][r] = exp2f(L2E * s[qs][ks][r]) * linv[qs][r];

        __syncthreads();   // prior iteration's P reads complete
        #pragma unroll
        for (int qs = 0; qs < 2; ++qs)
            #pragma unroll
            for (int ks = 0; ks < 2; ++ks)
                #pragma unroll
                for (int r = 0; r < 4; ++r)
                    P[qh * 32 + qs * 16 + quad * 4 + r][kw * 32 + ks * 16 + l16] = f2bf(p[qs][ks][r]);

        // attention colsums for this wave's 32-key strip (half of q rows each)
        #pragma unroll
        for (int ks = 0; ks < 2; ++ks) {
            float cs = p[0][ks][0] + p[0][ks][1] + p[0][ks][2] + p[0][ks][3]
                     + p[1][ks][0] + p[1][ks][1] + p[1][ks][2] + p[1][ks][3];
            cs += __shfl_xor(cs, 16, 64);
            cs += __shfl_xor(cs, 32, 64);
            if (quad == 0)
                atomicAdd(&attnacc[(size_t)b * NPIX + k0 + kw * 32 + ks * 16 + l16], cs);
        }
        __syncthreads();   // P visible to all waves

        // prefetch next tile's G fragments (wraps harmlessly on last iter)
        const int kn = (k0 + 128) & (NPIX - 1);
        #pragma unroll
        for (int st = 0; st < 8; ++st) {
            const unsigned short* gs = Gb + (size_t)st * (NPIX * 32) + quad * 8;
            gb[st][0] = *(const bf16x8*)(gs + (size_t)(kn + kw * 32 + l16) * 32);
            gb[st][1] = *(const bf16x8*)(gs + (size_t)(kn + kw * 32 + 16 + l16) * 32);
        }

        // PV: this wave's 64-c strip over the 128-key tile
        #pragma unroll
        for (int ks = 0; ks < 4; ++ks) {
            bf16x8 pa[4];
            #pragma unroll
            for (int qs = 0; qs < 4; ++qs)
                pa[qs] = *(const bf16x8*)&P[qs * 16 + l16][ks * 32 + quad * 8];
            const unsigned short* vs = Vb + ((size_t)(k0 >> 5) + ks) * (CH * 32) + quad * 8;
            #pragma unroll
            for (int ct = 0; ct < 4; ++ct) {
                bf16x8 vb = *(const bf16x8*)(vs + (size_t)(cb0 + ct * 16 + l16) * 32);
                #pragma unroll
                for (int qs = 0; qs < 4; ++qs)
                    O[qs][ct] = MFMA16(pa[qs], vb, O[qs][ct]);
            }
        }
    }

    #pragma unroll
    for (int qs = 0; qs < 4; ++qs) {
        #pragma unroll
        for (int ct = 0; ct < 4; ++ct) {
            const int c = cb0 + ct * 16 + l16;
            *(f32x4*)&outres[((size_t)b * CH + c) * NPIX + q0 + qs * 16 + quad * 4] = O[qs][ct];
        }
    }
}

__global__ __launch_bounds__(256) void attn_fin_kernel(
    const float* __restrict__ acc, float* __restrict__ outa)
{
    const int i = blockIdx.x * 256 + threadIdx.x;
    if (i < BATCH * NPIX) outa[i] = acc[i] * (1.0f / (float)NPIX);
}

extern "C" void kernel_launch(void* const* d_in, const int* in_sizes, int n_in,
                              void* d_out, int out_size, void* d_ws, size_t ws_size,
                              hipStream_t stream)
{
    (void)in_sizes; (void)n_in; (void)out_size; (void)ws_size;
    const float* x  = (const float*)d_in[0];
    const float* Wf = (const float*)d_in[1];
    const float* bf = (const float*)d_in[2];
    const float* Wg = (const float*)d_in[3];
    const float* bg = (const float*)d_in[4];
    const float* Wh = (const float*)d_in[5];
    const float* bh = (const float*)d_in[6];
    float* out = (float*)d_out;

    unsigned short* Xp = (unsigned short*)d_ws;                      // 4*16*4096*32
    unsigned short* Wc = Xp + (size_t)BATCH * 16 * NPIX * 32;        // 1024*512
    unsigned short* F  = Wc + (size_t)1024 * CH;                     // 4*4096*256
    unsigned short* G  = F + (size_t)BATCH * NPIX * HCH;             // 4*8*4096*32
    unsigned short* V  = G + (size_t)BATCH * NPIX * HCH;             // 4*128*512*32
    float* rowl    = (float*)(V + (size_t)BATCH * NPIX * CH);        // 4*4096
    float* attnacc = rowl + (size_t)BATCH * NPIX;                    // 4*4096

    hipMemsetAsync(rowl, 0, (size_t)2 * BATCH * NPIX * sizeof(float), stream);

    convert_w_kernel<<<512, 256, 0, stream>>>(Wf, Wg, Wh, Wc);
    convert_x_kernel<<<dim3(NPIX / 64, 16, BATCH), 256, 0, stream>>>(x, Xp);

    proj_fg_kernel<<<dim3(NPIX / 128, 4, BATCH), 256, 0, stream>>>(Wc, Xp, bf, bg, F, G);
    proj_v_kernel<<<dim3(4, NPIX / 128, BATCH), 256, 0, stream>>>(Wc, Xp, bh, V);

    stats_kernel<<<256, 512, 0, stream>>>(F, G, rowl);
    apply_kernel<<<256, 512, 0, stream>>>(F, G, V, rowl, out, attnacc);

    attn_fin_kernel<<<BATCH * NPIX / 256, 256, 0, stream>>>(
        attnacc, out + (size_t)BATCH * CH * NPIX);
}

// Round 6
// 537.507 us; speedup vs baseline: 31.2672x; 1.0196x over previous
//
#include <hip/hip_runtime.h>
#include <cmath>

#define BATCH 4
#define CH    512
#define HCH   256
#define NPIX  4096
#define L2E   1.44269504088896340736f

typedef __attribute__((ext_vector_type(8))) short bf16x8;
typedef __attribute__((ext_vector_type(4))) float f32x4;

#define MFMA16(a, b, c) __builtin_amdgcn_mfma_f32_16x16x32_bf16((a), (b), (c), 0, 0, 0)

__device__ __forceinline__ unsigned short f2bf(float f) {
    unsigned int u = __float_as_uint(f);
    return (unsigned short)((u + 0x7fffu + ((u >> 16) & 1u)) >> 16);
}
__device__ __forceinline__ ushort4 pack4(float a, float b, float c, float d) {
    ushort4 u; u.x = f2bf(a); u.y = f2bf(b); u.z = f2bf(c); u.w = f2bf(d); return u;
}

// ---------------------------------------------------------------------------
// Wc[1024][512] bf16 = concat(Wf, Wg, Wh) rows, K-contiguous.
// ---------------------------------------------------------------------------
__global__ __launch_bounds__(256) void convert_w_kernel(
    const float* __restrict__ Wf, const float* __restrict__ Wg,
    const float* __restrict__ Wh, unsigned short* __restrict__ Wc)
{
    const int idx = blockIdx.x * 256 + threadIdx.x;
    const int o  = idx >> 7;
    const int c4 = (idx & 127) * 4;
    const float* src = (o < HCH)     ? (Wf + (size_t)o * CH + c4)
                     : (o < 2 * HCH) ? (Wg + (size_t)(o - HCH) * CH + c4)
                                     : (Wh + (size_t)(o - 2 * HCH) * CH + c4);
    float4 v = *(const float4*)src;
    *(ushort4*)&Wc[(size_t)o * CH + c4] = pack4(v.x, v.y, v.z, v.w);
}

// ---------------------------------------------------------------------------
// X' swizzle: x fp32 [b][512][4096] -> bf16 [b][cb=16][n=4096][co=32].
// ---------------------------------------------------------------------------
__global__ __launch_bounds__(256) void convert_x_kernel(
    const float* __restrict__ x, unsigned short* __restrict__ Xp)
{
    __shared__ unsigned short Lt[64][40];
    const int b  = blockIdx.z;
    const int cb = blockIdx.y;
    const int n0 = blockIdx.x * 64;
    const int t  = threadIdx.x;
    const int cr = t >> 4;
    const int f4 = t & 15;
    #pragma unroll
    for (int p = 0; p < 2; ++p) {
        const int c = p * 16 + cr;
        float4 v = *(const float4*)(x + ((size_t)b * CH + cb * 32 + c) * NPIX + n0 + f4 * 4);
        Lt[f4 * 4 + 0][c] = f2bf(v.x);
        Lt[f4 * 4 + 1][c] = f2bf(v.y);
        Lt[f4 * 4 + 2][c] = f2bf(v.z);
        Lt[f4 * 4 + 3][c] = f2bf(v.w);
    }
    __syncthreads();
    const int n  = t >> 2;
    const int ch = t & 3;
    uint4 u = *(const uint4*)&Lt[n][ch * 8];
    *(uint4*)&Xp[((size_t)b * 16 + cb) * (NPIX * 32) + (size_t)(n0 + n) * 32 + ch * 8] = u;
}

// ---------------------------------------------------------------------------
// proj F/G (unchanged)
// ---------------------------------------------------------------------------
__global__ __launch_bounds__(256, 2) void proj_fg_kernel(
    const unsigned short* __restrict__ Wc, const unsigned short* __restrict__ Xp,
    const float* __restrict__ bf, const float* __restrict__ bg,
    unsigned short* __restrict__ F, unsigned short* __restrict__ G)
{
    const int b  = blockIdx.z;
    const int n0 = blockIdx.x * 128;
    const int o0 = blockIdx.y * 128;
    const int t  = threadIdx.x;
    const int wave = t >> 6, lane = t & 63, quad = lane >> 4, l16 = lane & 15;
    const int ow = o0 + wave * 32;

    f32x4 acc[2][8];
    #pragma unroll
    for (int ms = 0; ms < 2; ++ms)
        #pragma unroll
        for (int ns = 0; ns < 8; ++ns) acc[ms][ns] = (f32x4){0.f, 0.f, 0.f, 0.f};

    const unsigned short* xb = Xp + (size_t)b * 16 * (NPIX * 32);
    for (int st = 0; st < 16; ++st) {
        bf16x8 a0 = *(const bf16x8*)&Wc[(size_t)(ow + l16) * CH + st * 32 + quad * 8];
        bf16x8 a1 = *(const bf16x8*)&Wc[(size_t)(ow + 16 + l16) * CH + st * 32 + quad * 8];
        const unsigned short* xs = xb + (size_t)st * (NPIX * 32) + quad * 8;
        #pragma unroll
        for (int ns = 0; ns < 8; ++ns) {
            bf16x8 bb = *(const bf16x8*)(xs + (size_t)(n0 + ns * 16 + l16) * 32);
            acc[0][ns] = MFMA16(a0, bb, acc[0][ns]);
            acc[1][ns] = MFMA16(a1, bb, acc[1][ns]);
        }
    }

    const int orow = quad * 4;
    #pragma unroll
    for (int ms = 0; ms < 2; ++ms) {
        const int ob = ow + ms * 16 + orow;
        float bias[4];
        #pragma unroll
        for (int r = 0; r < 4; ++r)
            bias[r] = (o0 < HCH) ? bf[ob + r] : bg[ob + r - HCH];
        #pragma unroll
        for (int ns = 0; ns < 8; ++ns) {
            const int n = n0 + ns * 16 + l16;
            ushort4 u = pack4(acc[ms][ns][0] + bias[0], acc[ms][ns][1] + bias[1],
                              acc[ms][ns][2] + bias[2], acc[ms][ns][3] + bias[3]);
            if (o0 < HCH) {
                *(ushort4*)&F[((size_t)b * NPIX + n) * HCH + ob] = u;
            } else {
                const int og = ob - HCH;
                const int cb = og >> 5, co = og & 31;
                *(ushort4*)&G[((size_t)b * 8 + cb) * (NPIX * 32) + (size_t)n * 32 + co] = u;
            }
        }
    }
}

// ---------------------------------------------------------------------------
// proj V (unchanged)
// ---------------------------------------------------------------------------
__global__ __launch_bounds__(256, 2) void proj_v_kernel(
    const unsigned short* __restrict__ Wc, const unsigned short* __restrict__ Xp,
    const float* __restrict__ bh, unsigned short* __restrict__ V)
{
    const int b  = blockIdx.z;
    const int c0 = blockIdx.x * 128;
    const int p0 = blockIdx.y * 128;
    const int t  = threadIdx.x;
    const int wave = t >> 6, lane = t & 63, quad = lane >> 4, l16 = lane & 15;
    const int pw = p0 + wave * 32;

    f32x4 acc[2][8];
    #pragma unroll
    for (int ms = 0; ms < 2; ++ms)
        #pragma unroll
        for (int ns = 0; ns < 8; ++ns) acc[ms][ns] = (f32x4){0.f, 0.f, 0.f, 0.f};

    const unsigned short* xb = Xp + (size_t)b * 16 * (NPIX * 32);
    for (int st = 0; st < 16; ++st) {
        const unsigned short* xs = xb + (size_t)st * (NPIX * 32) + quad * 8;
        bf16x8 a0 = *(const bf16x8*)(xs + (size_t)(pw + l16) * 32);
        bf16x8 a1 = *(const bf16x8*)(xs + (size_t)(pw + 16 + l16) * 32);
        #pragma unroll
        for (int ns = 0; ns < 8; ++ns) {
            bf16x8 bb = *(const bf16x8*)&Wc[(size_t)(2 * HCH + c0 + ns * 16 + l16) * CH + st * 32 + quad * 8];
            acc[0][ns] = MFMA16(a0, bb, acc[0][ns]);
            acc[1][ns] = MFMA16(a1, bb, acc[1][ns]);
        }
    }

    float biasv[8];
    #pragma unroll
    for (int ns = 0; ns < 8; ++ns) biasv[ns] = bh[c0 + ns * 16 + l16];

    const int kb = pw >> 5;
    const int ko0 = quad * 4;
    #pragma unroll
    for (int ms = 0; ms < 2; ++ms) {
        #pragma unroll
        for (int ns = 0; ns < 8; ++ns) {
            const int c = c0 + ns * 16 + l16;
            ushort4 u = pack4(acc[ms][ns][0] + biasv[ns], acc[ms][ns][1] + biasv[ns],
                              acc[ms][ns][2] + biasv[ns], acc[ms][ns][3] + biasv[ns]);
            *(ushort4*)&V[((size_t)b * 128 + kb) * (CH * 32) + (size_t)c * 32 + ms * 16 + ko0] = u;
        }
    }
}

// ---------------------------------------------------------------------------
// Stats: 64q, 512 thr, k-half split -> grid 512 (2 blocks/CU).
// XCD map: b = xcd>>1, kh = xcd&1 (per-XCD G working set = 1 MB).
// ---------------------------------------------------------------------------
__global__ __launch_bounds__(512, 4) void stats_kernel(
    const unsigned short* __restrict__ F, const unsigned short* __restrict__ G,
    float* __restrict__ rowl)
{
    const int blk = blockIdx.x;
    const int xcd = blk & 7;
    const int b   = xcd >> 1;
    const int kh  = xcd & 1;
    const int q0  = (blk >> 3) * 64;
    const int t    = threadIdx.x;
    const int wave = t >> 6, lane = t & 63, quad = lane >> 4, l16 = lane & 15;
    const int qh = wave >> 2, kw = wave & 3;

    bf16x8 af[2][8];
    #pragma unroll
    for (int qs = 0; qs < 2; ++qs)
        #pragma unroll
        for (int st = 0; st < 8; ++st)
            af[qs][st] = *(const bf16x8*)&F[((size_t)b * NPIX + q0 + qh * 32 + qs * 16 + l16) * HCH + st * 32 + quad * 8];

    float ls[2][4];
    #pragma unroll
    for (int qs = 0; qs < 2; ++qs)
        #pragma unroll
        for (int r = 0; r < 4; ++r) ls[qs][r] = 0.f;

    const unsigned short* Gb = G + (size_t)b * 8 * (NPIX * 32);
    const int kbeg = kh * 2048, kend = kbeg + 2048;
    for (int k0 = kbeg; k0 < kend; k0 += 128) {
        const int kk = k0 + kw * 32;
        f32x4 s[2][2];
        #pragma unroll
        for (int qs = 0; qs < 2; ++qs)
            #pragma unroll
            for (int ks = 0; ks < 2; ++ks) s[qs][ks] = (f32x4){0.f, 0.f, 0.f, 0.f};
        #pragma unroll
        for (int st = 0; st < 8; ++st) {
            const unsigned short* gs = Gb + (size_t)st * (NPIX * 32) + quad * 8;
            bf16x8 b0 = *(const bf16x8*)(gs + (size_t)(kk + l16) * 32);
            bf16x8 b1 = *(const bf16x8*)(gs + (size_t)(kk + 16 + l16) * 32);
            s[0][0] = MFMA16(af[0][st], b0, s[0][0]);
            s[1][0] = MFMA16(af[1][st], b0, s[1][0]);
            s[0][1] = MFMA16(af[0][st], b1, s[0][1]);
            s[1][1] = MFMA16(af[1][st], b1, s[1][1]);
        }
        #pragma unroll
        for (int qs = 0; qs < 2; ++qs)
            #pragma unroll
            for (int r = 0; r < 4; ++r)
                ls[qs][r] += exp2f(L2E * s[qs][0][r]) + exp2f(L2E * s[qs][1][r]);
    }

    #pragma unroll
    for (int d = 1; d < 16; d <<= 1)
        #pragma unroll
        for (int qs = 0; qs < 2; ++qs)
            #pragma unroll
            for (int r = 0; r < 4; ++r) ls[qs][r] += __shfl_xor(ls[qs][r], d, 64);

    if (l16 == 0) {
        #pragma unroll
        for (int qs = 0; qs < 2; ++qs)
            #pragma unroll
            for (int r = 0; r < 4; ++r)
                atomicAdd(&rowl[(size_t)b * NPIX + q0 + qh * 32 + qs * 16 + quad * 4 + r], ls[qs][r]);
    }
}

// ---------------------------------------------------------------------------
// Apply: 64q x 256c-half per block, 512 thr, grid 512 (2 blocks/CU).
// XCD map: b = xcd>>1, ch = xcd&1 -> per-XCD L2 set = G 2MB + V-half 2MB.
// Double-buffered P, ONE barrier per 128-key tile. QK duplicated across the
// c-pair; only ch==0 emits attention colsums.
// ---------------------------------------------------------------------------
__global__ __launch_bounds__(512, 4) void apply_kernel(
    const unsigned short* __restrict__ F, const unsigned short* __restrict__ G,
    const unsigned short* __restrict__ V, const float* __restrict__ rowl,
    float* __restrict__ outres, float* __restrict__ attnacc)
{
    __shared__ unsigned short P[2][64][136];   // 34.8 KB
    const int blk = blockIdx.x;
    const int xcd = blk & 7;
    const int b   = xcd >> 1;
    const int ch  = xcd & 1;
    const int q0  = (blk >> 3) * 64;
    const int t    = threadIdx.x;
    const int wave = t >> 6, lane = t & 63, quad = lane >> 4, l16 = lane & 15;
    const int qh = wave >> 2, kw = wave & 3;
    const int cw = ch * 256 + wave * 32;    // wave's 32-c strip

    bf16x8 af[2][8];
    #pragma unroll
    for (int qs = 0; qs < 2; ++qs)
        #pragma unroll
        for (int st = 0; st < 8; ++st)
            af[qs][st] = *(const bf16x8*)&F[((size_t)b * NPIX + q0 + qh * 32 + qs * 16 + l16) * HCH + st * 32 + quad * 8];

    float linv[2][4];
    #pragma unroll
    for (int qs = 0; qs < 2; ++qs)
        #pragma unroll
        for (int r = 0; r < 4; ++r)
            linv[qs][r] = 1.0f / rowl[(size_t)b * NPIX + q0 + qh * 32 + qs * 16 + quad * 4 + r];

    f32x4 O[4][2];
    #pragma unroll
    for (int qs = 0; qs < 4; ++qs)
        #pragma unroll
        for (int ct = 0; ct < 2; ++ct) O[qs][ct] = (f32x4){0.f, 0.f, 0.f, 0.f};

    const unsigned short* Gb = G + (size_t)b * 8 * (NPIX * 32);
    const unsigned short* Vb = V + (size_t)b * 128 * (CH * 32);

    int buf = 0;
    for (int k0 = 0; k0 < NPIX; k0 += 128) {
        const int kk = k0 + kw * 32;
        f32x4 s[2][2];
        #pragma unroll
        for (int qs = 0; qs < 2; ++qs)
            #pragma unroll
            for (int ks = 0; ks < 2; ++ks) s[qs][ks] = (f32x4){0.f, 0.f, 0.f, 0.f};
        #pragma unroll
        for (int st = 0; st < 8; ++st) {
            const unsigned short* gs = Gb + (size_t)st * (NPIX * 32) + quad * 8;
            bf16x8 b0 = *(const bf16x8*)(gs + (size_t)(kk + l16) * 32);
            bf16x8 b1 = *(const bf16x8*)(gs + (size_t)(kk + 16 + l16) * 32);
            s[0][0] = MFMA16(af[0][st], b0, s[0][0]);
            s[1][0] = MFMA16(af[1][st], b0, s[1][0]);
            s[0][1] = MFMA16(af[0][st], b1, s[0][1]);
            s[1][1] = MFMA16(af[1][st], b1, s[1][1]);
        }

        float p[2][2][4];
        #pragma unroll
        for (int qs = 0; qs < 2; ++qs)
            #pragma unroll
            for (int ks = 0; ks < 2; ++ks)
                #pragma unroll
                for (int r = 0; r < 4; ++r)
                    p[qs][ks][r] = exp2f(L2E * s[qs][ks][r]) * linv[qs][r];

        #pragma unroll
        for (int qs = 0; qs < 2; ++qs)
            #pragma unroll
            for (int ks = 0; ks < 2; ++ks)
                #pragma unroll
                for (int r = 0; r < 4; ++r)
                    P[buf][qh * 32 + qs * 16 + quad * 4 + r][kw * 32 + ks * 16 + l16] = f2bf(p[qs][ks][r]);

        if (ch == 0) {
            #pragma unroll
            for (int ks = 0; ks < 2; ++ks) {
                float cs = p[0][ks][0] + p[0][ks][1] + p[0][ks][2] + p[0][ks][3]
                         + p[1][ks][0] + p[1][ks][1] + p[1][ks][2] + p[1][ks][3];
                cs += __shfl_xor(cs, 16, 64);
                cs += __shfl_xor(cs, 32, 64);
                if (quad == 0)
                    atomicAdd(&attnacc[(size_t)b * NPIX + kk + ks * 16 + l16], cs);
            }
        }

        __syncthreads();   // P[buf] complete; t+1 writes go to buf^1 (race-free)

        #pragma unroll
        for (int ks = 0; ks < 4; ++ks) {
            bf16x8 pa[4];
            #pragma unroll
            for (int qs = 0; qs < 4; ++qs)
                pa[qs] = *(const bf16x8*)&P[buf][qs * 16 + l16][ks * 32 + quad * 8];
            const unsigned short* vs = Vb + ((size_t)(k0 >> 5) + ks) * (CH * 32) + quad * 8;
            #pragma unroll
            for (int ct = 0; ct < 2; ++ct) {
                bf16x8 vb = *(const bf16x8*)(vs + (size_t)(cw + ct * 16 + l16) * 32);
                #pragma unroll
                for (int qs = 0; qs < 4; ++qs)
                    O[qs][ct] = MFMA16(pa[qs], vb, O[qs][ct]);
            }
        }
        buf ^= 1;
    }

    #pragma unroll
    for (int qs = 0; qs < 4; ++qs) {
        #pragma unroll
        for (int ct = 0; ct < 2; ++ct) {
            const int c = cw + ct * 16 + l16;
            *(f32x4*)&outres[((size_t)b * CH + c) * NPIX + q0 + qs * 16 + quad * 4] = O[qs][ct];
        }
    }
}

__global__ __launch_bounds__(256) void attn_fin_kernel(
    const float* __restrict__ acc, float* __restrict__ outa)
{
    const int i = blockIdx.x * 256 + threadIdx.x;
    if (i < BATCH * NPIX) outa[i] = acc[i] * (1.0f / (float)NPIX);
}

extern "C" void kernel_launch(void* const* d_in, const int* in_sizes, int n_in,
                              void* d_out, int out_size, void* d_ws, size_t ws_size,
                              hipStream_t stream)
{
    (void)in_sizes; (void)n_in; (void)out_size; (void)ws_size;
    const float* x  = (const float*)d_in[0];
    const float* Wf = (const float*)d_in[1];
    const float* bf = (const float*)d_in[2];
    const float* Wg = (const float*)d_in[3];
    const float* bg = (const float*)d_in[4];
    const float* Wh = (const float*)d_in[5];
    const float* bh = (const float*)d_in[6];
    float* out = (float*)d_out;

    unsigned short* Xp = (unsigned short*)d_ws;                      // 4*16*4096*32
    unsigned short* Wc = Xp + (size_t)BATCH * 16 * NPIX * 32;        // 1024*512
    unsigned short* F  = Wc + (size_t)1024 * CH;                     // 4*4096*256
    unsigned short* G  = F + (size_t)BATCH * NPIX * HCH;             // 4*8*4096*32
    unsigned short* V  = G + (size_t)BATCH * NPIX * HCH;             // 4*128*512*32
    float* rowl    = (float*)(V + (size_t)BATCH * NPIX * CH);        // 4*4096
    float* attnacc = rowl + (size_t)BATCH * NPIX;                    // 4*4096

    hipMemsetAsync(rowl, 0, (size_t)2 * BATCH * NPIX * sizeof(float), stream);

    convert_w_kernel<<<512, 256, 0, stream>>>(Wf, Wg, Wh, Wc);
    convert_x_kernel<<<dim3(NPIX / 64, 16, BATCH), 256, 0, stream>>>(x, Xp);

    proj_fg_kernel<<<dim3(NPIX / 128, 4, BATCH), 256, 0, stream>>>(Wc, Xp, bf, bg, F, G);
    proj_v_kernel<<<dim3(4, NPIX / 128, BATCH), 256, 0, stream>>>(Wc, Xp, bh, V);

    stats_kernel<<<512, 512, 0, stream>>>(F, G, rowl);
    apply_kernel<<<512, 512, 0, stream>>>(F, G, V, rowl, out, attnacc);

    attn_fin_kernel<<<BATCH * NPIX / 256, 256, 0, stream>>>(
        attnacc, out + (size_t)BATCH * CH * NPIX);
}